// Round 7
// baseline (352.006 us; speedup 1.0000x reference)
//
#include <hip/hip_runtime.h>

// Laplacian-kernel regression, fused, bf16 MFMA 16x16x32 — "direct fragment"
// structure: X/Z/W are pre-swizzled in d_ws into MFMA fragment-tile order
// (each 16-row x 32-k fragment = contiguous 1 KB in lane-major order), so
// every A/B operand is ONE coalesced global_load_dwordx4 — no LDS staging,
// no staging barriers. LDS holds only sP (P's C->A layout transform):
// 2 __syncthreads per m-tile (R6 had ~25 and was barrier-drain-bound).
//   d2 = ||x||^2 + ||z||^2 - 2 X.Z^T ; P = exp(-sqrt(d2)/10) ; out = P @ W
// 256 thr / 4 waves; wave = 64x64 in QK (wave grid 1x4 over BN=256) and in
// PV (y-band per wave). Grid (128 row-tiles, 4 chunks) = 512 blocks =
// 2 blocks/CU (sP 33.8 KB); XCD = bx%8 -> X 1 MB/XCD, Z/W L2-resident.
// MCH=4 keeps atomic epilogue volume at 32 MB (R5 lesson).

using frag8 = __attribute__((ext_vector_type(8))) short;   // 8 bf16 (4 VGPRs)
using f32x4 = __attribute__((ext_vector_type(4))) float;   // 16x16 C/D frag

constexpr int Nn = 8192, Mm = 8192, Dd = 512, Yd = 256;
constexpr int BM = 64, BN = 256;
constexpr int MCH = 4, MPER = Mm / MCH, MT = MPER / BN;    // 2048, 8
constexpr int LDP = BN + 8;    // 264 ushort: rows 528 B = 33*16 (b128-aligned)

// Fragment-tile layout: tile(g, c) = rows [16g,16g+16) x k [32c,32c+32),
// stored at (g*(K/32) + c)*512 ushorts, element (r,k) at lane-major byte
// (r%16 + 16*((k%32)/8))*16 + (k%8)*2  ==  lane*16 + j*2.
// Xf/Zf: K=512 (16 k-groups); Wf: rows=y (256), K=z (8192, 256 k-groups).

// workspace layout (bytes)
constexpr size_t OFF_XF  = 0;                               // 8 MB
constexpr size_t OFF_ZF  = OFF_XF + (size_t)Nn * Dd * 2;    // 8 MB
constexpr size_t OFF_WF  = OFF_ZF + (size_t)Mm * Dd * 2;    // 4 MB
constexpr size_t OFF_XSQ = OFF_WF + (size_t)Yd * Mm * 2;
constexpr size_t OFF_ZSQ = OFF_XSQ + (size_t)Nn * 4;
constexpr size_t WS_NEED = OFF_ZSQ + (size_t)Mm * 4;        // ~20.1 MB

__device__ __forceinline__ ushort f2bf(float f) {
    unsigned u = __builtin_bit_cast(unsigned, f);
    u += 0x7FFFu + ((u >> 16) & 1u);          // RNE; inputs finite/normal
    return (ushort)(u >> 16);
}

// ---- prep: swizzle X,Z (cast + norms) and W (cast + transpose) into
//      fragment-tile order. One wave owns one 16-row group (X/Z) or one
//      16y x 32z tile (W). Grid: 256 blocks X/Z + 1024 blocks W. ----
__global__ __launch_bounds__(256) void prep_swizzle(
    const float* __restrict__ X, const float* __restrict__ Z,
    const float* __restrict__ W, ushort* __restrict__ Xf,
    ushort* __restrict__ Zf, ushort* __restrict__ Wf,
    float* __restrict__ xsq, float* __restrict__ zsq)
{
    const int wid = threadIdx.x >> 6, lane = threadIdx.x & 63;
    const int l16 = lane & 15, quad = lane >> 4;
    const int b = blockIdx.x;
    if (b < 256) {
        const int w = b * 4 + wid;                    // 0..1023 row-groups
        const float* src = (w < 512) ? X : Z;
        ushort* dst = (w < 512) ? Xf : Zf;
        float* nrm = (w < 512) ? xsq : zsq;
        const int g = (w < 512) ? w : w - 512;
        const int row = g * 16 + l16;
        float sq = 0.0f;
        #pragma unroll
        for (int kg = 0; kg < 16; ++kg) {
            const float* s = src + (size_t)row * Dd + kg * 32 + quad * 8;
            const float4 v0 = ((const float4*)s)[0];
            const float4 v1 = ((const float4*)s)[1];
            sq += v0.x*v0.x + v0.y*v0.y + v0.z*v0.z + v0.w*v0.w
                + v1.x*v1.x + v1.y*v1.y + v1.z*v1.z + v1.w*v1.w;
            uint4 pk;
            pk.x = (unsigned)f2bf(v0.x) | ((unsigned)f2bf(v0.y) << 16);
            pk.y = (unsigned)f2bf(v0.z) | ((unsigned)f2bf(v0.w) << 16);
            pk.z = (unsigned)f2bf(v1.x) | ((unsigned)f2bf(v1.y) << 16);
            pk.w = (unsigned)f2bf(v1.z) | ((unsigned)f2bf(v1.w) << 16);
            *(uint4*)(dst + ((size_t)g * 16 + kg) * 512 + lane * 8) = pk;
        }
        sq += __shfl_xor(sq, 16);
        sq += __shfl_xor(sq, 32);
        if (lane < 16) nrm[row] = sq;
    } else {
        const int tw = (b - 256) * 4 + wid;           // 0..4095 W tiles
        const int yg = tw & 15, zg = tw >> 4;
        const int y = yg * 16 + l16, z0 = zg * 32 + quad * 8;
        ushort r[8];
        #pragma unroll
        for (int jj = 0; jj < 8; ++jj)
            r[jj] = f2bf(W[(size_t)(z0 + jj) * Yd + y]);
        uint4 pk;
        pk.x = (unsigned)r[0] | ((unsigned)r[1] << 16);
        pk.y = (unsigned)r[2] | ((unsigned)r[3] << 16);
        pk.z = (unsigned)r[4] | ((unsigned)r[5] << 16);
        pk.w = (unsigned)r[6] | ((unsigned)r[7] << 16);
        *(uint4*)(Wf + ((size_t)yg * 256 + zg) * 512 + lane * 8) = pk;
    }
}

// ---- main fused kernel ----
__global__ __launch_bounds__(256, 2) void laplace_direct(
    const ushort* __restrict__ Xf, const ushort* __restrict__ Zf,
    const ushort* __restrict__ Wf, const float* __restrict__ xsqg,
    const float* __restrict__ zsqg, float* __restrict__ O)
{
    __shared__ ushort sP[64 * LDP];                   // 33.8 KB — only LDS use
    const int t = threadIdx.x, wid = t >> 6, lane = t & 63;
    const int l16 = lane & 15, quad = lane >> 4;
    const int row0  = blockIdx.x * BM;                // XCD = blockIdx.x % 8
    const int zbase = blockIdx.y * MPER;

    // row norms for this block's 64 rows, in registers (C/D row = quad*4+r)
    float xs[4][4];
    #pragma unroll
    for (int i = 0; i < 4; ++i)
        #pragma unroll
        for (int r = 0; r < 4; ++r)
            xs[i][r] = xsqg[row0 + 16 * i + quad * 4 + r];

    // fragment base pointers (lane offset folded in)
    const ushort* pa = Xf + ((size_t)(row0 >> 4) * 16) * 512 + lane * 8;
    const ushort* pb0 = Zf + ((size_t)((zbase >> 4) + wid * 4) * 16) * 512 + lane * 8;
    const ushort* pw = Wf + ((size_t)(wid * 4) * 256 + (zbase >> 5)) * 512 + lane * 8;

    f32x4 Oa[4][4];
    #pragma unroll
    for (int i = 0; i < 4; ++i)
        #pragma unroll
        for (int j = 0; j < 4; ++j)
            #pragma unroll
            for (int r = 0; r < 4; ++r) Oa[i][j][r] = 0.0f;

    for (int mt = 0; mt < MT; ++mt) {
        const ushort* pb = pb0 + (size_t)mt * 16 * 16 * 512;   // +256 z-rows
        float zs4[4];
        #pragma unroll
        for (int j = 0; j < 4; ++j)
            zs4[j] = zsqg[zbase + mt * 256 + wid * 64 + 16 * j + l16];

        f32x4 S[4][4];
        #pragma unroll
        for (int i = 0; i < 4; ++i)
            #pragma unroll
            for (int j = 0; j < 4; ++j)
                #pragma unroll
                for (int r = 0; r < 4; ++r) S[i][j][r] = 0.0f;

        // ---- QK: no LDS, no barriers — pure load/MFMA interleave ----
        #pragma unroll
        for (int kk = 0; kk < 16; ++kk) {
            frag8 a[4], b[4];
            #pragma unroll
            for (int i = 0; i < 4; ++i)
                a[i] = *(const frag8*)(pa + (size_t)i * 8192 + kk * 512);
            #pragma unroll
            for (int j = 0; j < 4; ++j)
                b[j] = *(const frag8*)(pb + (size_t)j * 8192 + kk * 512);
            #pragma unroll
            for (int i = 0; i < 4; ++i)
                #pragma unroll
                for (int j = 0; j < 4; ++j)
                    S[i][j] = __builtin_amdgcn_mfma_f32_16x16x32_bf16(
                        a[i], b[j], S[i][j], 0, 0, 0);
        }

        __syncthreads();   // prev m-tile's PV done reading sP

        // ---- transform -> sP (C/D: col=l16, row=quad*4+r) ----
        #pragma unroll
        for (int i = 0; i < 4; ++i) {
            const int xl = 16 * i + quad * 4;
            #pragma unroll
            for (int j = 0; j < 4; ++j) {
                const int col = wid * 64 + 16 * j + l16;
                const float zz = zs4[j];
                #pragma unroll
                for (int r = 0; r < 4; ++r) {
                    const float d2 = fmaxf(xs[i][r] + zz - 2.0f * S[i][j][r], 0.0f);
                    sP[(xl + r) * LDP + col] = f2bf(__expf(-0.1f * __builtin_sqrtf(d2)));
                }
            }
        }
        __syncthreads();   // sP visible to all waves

        // ---- PV: O += P[64x256] . W[256x256]; A from LDS, B direct ----
        #pragma unroll
        for (int pv = 0; pv < 8; ++pv) {              // z-group = pv (32 z each)
            frag8 ap[4], bw[4];
            #pragma unroll
            for (int i = 0; i < 4; ++i)
                ap[i] = *(const frag8*)(sP + (16 * i + l16) * LDP + pv * 32 + quad * 8);
            #pragma unroll
            for (int j = 0; j < 4; ++j)
                bw[j] = *(const frag8*)(pw + (size_t)j * 131072 + (mt * 8 + pv) * 512);
            #pragma unroll
            for (int j = 0; j < 4; ++j)
                #pragma unroll
                for (int i = 0; i < 4; ++i)
                    Oa[i][j] = __builtin_amdgcn_mfma_f32_16x16x32_bf16(
                        ap[i], bw[j], Oa[i][j], 0, 0, 0);
        }
    }

    // ---- epilogue: combine 4 M-chunks via fp32 atomics (XCD-local) ----
    #pragma unroll
    for (int i = 0; i < 4; ++i) {
        const int xr = row0 + 16 * i + quad * 4;
        #pragma unroll
        for (int j = 0; j < 4; ++j) {
            const int col = wid * 64 + 16 * j + l16;
            #pragma unroll
            for (int r = 0; r < 4; ++r)
                atomicAdd(&O[(size_t)(xr + r) * Yd + col], Oa[i][j][r]);
        }
    }
}

// ---- fallback (fp32 VALU fused kernel) if workspace is too small ----
constexpr int FBM = 64, FBN = 64, FBK = 64;
constexpr int FMCH = 4, FMCHUNK = Mm / FMCH, FMSTEPS = FMCHUNK / FBN, FDSTEPS = Dd / FBK;
constexpr int FLDA = FBK + 1, FLDSS = FBN + 1;

__global__ __launch_bounds__(256, 3) void laplace_fused_v1(
    const float* __restrict__ X, const float* __restrict__ Z,
    const float* __restrict__ W, float* __restrict__ O)
{
    __shared__ float sX[FBM * FLDA];
    __shared__ float sZ[FBN * FLDA];
    __shared__ float sS[FBM * FLDSS];
    const int t = threadIdx.x, pr = t >> 4, pc = t & 15, sc4 = pc * 4;
    const int row0 = blockIdx.x * FBM, mbase = blockIdx.y * FMCHUNK;
    float o[4][4][4];
    #pragma unroll
    for (int i = 0; i < 4; ++i)
        for (int yb = 0; yb < 4; ++yb)
            for (int j = 0; j < 4; ++j) o[i][yb][j] = 0.0f;
    for (int ms = 0; ms < FMSTEPS; ++ms) {
        const int zrow0 = mbase + ms * FBN;
        float s[4][4];
        #pragma unroll
        for (int i = 0; i < 4; ++i)
            for (int j = 0; j < 4; ++j) s[i][j] = 0.0f;
        for (int kk = 0; kk < FDSTEPS; ++kk) {
            const int k0 = kk * FBK;
            __syncthreads();
            #pragma unroll
            for (int rep = 0; rep < 4; ++rep) {
                const int r = pr + rep * 16;
                const float4 xv = *reinterpret_cast<const float4*>(X + (size_t)(row0 + r) * Dd + k0 + sc4);
                const float4 zv = *reinterpret_cast<const float4*>(Z + (size_t)(zrow0 + r) * Dd + k0 + sc4);
                float* dx = sX + r * FLDA + sc4;
                dx[0] = xv.x; dx[1] = xv.y; dx[2] = xv.z; dx[3] = xv.w;
                float* dz = sZ + r * FLDA + sc4;
                dz[0] = zv.x; dz[1] = zv.y; dz[2] = zv.z; dz[3] = zv.w;
            }
            __syncthreads();
            #pragma unroll 4
            for (int k = 0; k < FBK; ++k) {
                float xr[4], zc[4];
                #pragma unroll
                for (int i = 0; i < 4; ++i) xr[i] = sX[(pr * 4 + i) * FLDA + k];
                #pragma unroll
                for (int j = 0; j < 4; ++j) zc[j] = sZ[(pc * 4 + j) * FLDA + k];
                #pragma unroll
                for (int i = 0; i < 4; ++i)
                    #pragma unroll
                    for (int j = 0; j < 4; ++j) {
                        const float d = xr[i] - zc[j];
                        s[i][j] = fmaf(d, d, s[i][j]);
                    }
            }
        }
        #pragma unroll
        for (int i = 0; i < 4; ++i)
            for (int j = 0; j < 4; ++j)
                sS[(pr * 4 + i) * FLDSS + sc4 + j] = __expf(-sqrtf(s[i][j]) * 0.1f);
        __syncthreads();
        #pragma unroll 2
        for (int c = 0; c < FBN; ++c) {
            float sv[4];
            #pragma unroll
            for (int i = 0; i < 4; ++i) sv[i] = sS[(pr * 4 + i) * FLDSS + c];
            const float* wrow = W + (size_t)(zrow0 + c) * Yd;
            #pragma unroll
            for (int yb = 0; yb < 4; ++yb) {
                const float4 wv = *reinterpret_cast<const float4*>(wrow + yb * 64 + sc4);
                #pragma unroll
                for (int i = 0; i < 4; ++i) {
                    o[i][yb][0] = fmaf(sv[i], wv.x, o[i][yb][0]);
                    o[i][yb][1] = fmaf(sv[i], wv.y, o[i][yb][1]);
                    o[i][yb][2] = fmaf(sv[i], wv.z, o[i][yb][2]);
                    o[i][yb][3] = fmaf(sv[i], wv.w, o[i][yb][3]);
                }
            }
        }
        __syncthreads();
    }
    #pragma unroll
    for (int i = 0; i < 4; ++i) {
        const size_t rbase = (size_t)(row0 + pr * 4 + i) * Yd;
        #pragma unroll
        for (int yb = 0; yb < 4; ++yb)
            for (int j = 0; j < 4; ++j)
                atomicAdd(O + rbase + yb * 64 + sc4 + j, o[i][yb][j]);
    }
}

extern "C" void kernel_launch(void* const* d_in, const int* in_sizes, int n_in,
                              void* d_out, int out_size, void* d_ws, size_t ws_size,
                              hipStream_t stream) {
    const float* X = (const float*)d_in[0];   // batch   [8192, 512]
    const float* Z = (const float*)d_in[1];   // centers [8192, 512]
    const float* W = (const float*)d_in[2];   // weight  [8192, 256]
    float* O = (float*)d_out;                 // pred    [8192, 256]

    hipMemsetAsync(d_out, 0, (size_t)out_size * sizeof(float), stream);

    if (ws_size < WS_NEED) {
        dim3 grid(Nn / FBM, FMCH);
        laplace_fused_v1<<<grid, dim3(256), 0, stream>>>(X, Z, W, O);
        return;
    }

    char* ws = (char*)d_ws;
    ushort* Xf  = (ushort*)(ws + OFF_XF);
    ushort* Zf  = (ushort*)(ws + OFF_ZF);
    ushort* Wf  = (ushort*)(ws + OFF_WF);
    float*  xsq = (float*)(ws + OFF_XSQ);
    float*  zsq = (float*)(ws + OFF_ZSQ);

    prep_swizzle<<<dim3(256 + 1024), dim3(256), 0, stream>>>(
        X, Z, W, Xf, Zf, Wf, xsq, zsq);

    laplace_direct<<<dim3(Nn / BM, MCH), dim3(256), 0, stream>>>(
        Xf, Zf, Wf, xsq, zsq, O);
}

// Round 8
// 302.750 us; speedup vs baseline: 1.1627x; 1.1627x over previous
//
#include <hip/hip_runtime.h>

// Laplacian-kernel regression, fused, bf16 MFMA 16x16x32 — hybrid structure:
//   - X tile (64 rows x K=512, fragment layout, 64 KB) staged in LDS ONCE per
//     block -> QK inner loop has zero barriers and zero X re-fetch.
//   - Z and W read directly from global in MFMA-fragment layout (1 KB/frag,
//     one dwordx4 per lane) -> L2-resident windows, no staging.
//   - LDS round-trip only for P (C->A layout), 2 __syncthreads per m-tile.
//   d2 = ||x||^2 + ||z||^2 - 2 X.Z^T ; P = exp(-sqrt(d2)/10) ; out = P @ W
// 256 thr / 4 waves; QK wave = 64x64 (wave grid 1x4 over BN=256); PV wave =
// 64 y-band. Grid (128 row-tiles, MCH=2) = 256 blocks = 1/CU (LDS 97 KB).
// Both chunks of a row-tile share an XCD (128 % 8 == 0) -> atomics XCD-local,
// 16 MB volume. R7 lesson: direct-fragment EVERYTHING = 3x over L2 BW
// (FETCH 549 MB); LDS must amplify the reused operand (X: 4x across waves).

using frag8 = __attribute__((ext_vector_type(8))) short;   // 8 bf16 (4 VGPRs)
using f32x4 = __attribute__((ext_vector_type(4))) float;   // 16x16 C/D frag

constexpr int Nn = 8192, Mm = 8192, Dd = 512, Yd = 256;
constexpr int BM = 64, BN = 256;
constexpr int MCH = 2, MPER = Mm / MCH, MT = MPER / BN;    // 4096, 16
constexpr int LDP = BN + 8;    // 264 ushort: rows 528 B (16B-aligned)

// Fragment-tile layout: tile(g, c) = rows [16g,16g+16) x k [32c,32c+32),
// stored at (g*(K/32) + c)*512 ushorts, element (r,k) at lane-major
// (r%16 + 16*((k%32)/8))*8 + (k%8) ushorts == lane*8 + j.
// Xf/Zf: K=512 (16 k-groups); Wf: rows=y (256), K=z (8192, 256 k-groups).

// workspace layout (bytes)
constexpr size_t OFF_XF  = 0;                               // 8 MB
constexpr size_t OFF_ZF  = OFF_XF + (size_t)Nn * Dd * 2;    // 8 MB
constexpr size_t OFF_WF  = OFF_ZF + (size_t)Mm * Dd * 2;    // 4 MB
constexpr size_t OFF_XSQ = OFF_WF + (size_t)Yd * Mm * 2;
constexpr size_t OFF_ZSQ = OFF_XSQ + (size_t)Nn * 4;
constexpr size_t WS_NEED = OFF_ZSQ + (size_t)Mm * 4;        // ~20.1 MB

__device__ __forceinline__ ushort f2bf(float f) {
    unsigned u = __builtin_bit_cast(unsigned, f);
    u += 0x7FFFu + ((u >> 16) & 1u);          // RNE; inputs finite/normal
    return (ushort)(u >> 16);
}

// ---- prep: swizzle X,Z (cast + norms) and W (cast + transpose) into
//      fragment-tile order. ----
__global__ __launch_bounds__(256) void prep_swizzle(
    const float* __restrict__ X, const float* __restrict__ Z,
    const float* __restrict__ W, ushort* __restrict__ Xf,
    ushort* __restrict__ Zf, ushort* __restrict__ Wf,
    float* __restrict__ xsq, float* __restrict__ zsq)
{
    const int wid = threadIdx.x >> 6, lane = threadIdx.x & 63;
    const int l16 = lane & 15, quad = lane >> 4;
    const int b = blockIdx.x;
    if (b < 256) {
        const int w = b * 4 + wid;                    // 0..1023 row-groups
        const float* src = (w < 512) ? X : Z;
        ushort* dst = (w < 512) ? Xf : Zf;
        float* nrm = (w < 512) ? xsq : zsq;
        const int g = (w < 512) ? w : w - 512;
        const int row = g * 16 + l16;
        float sq = 0.0f;
        #pragma unroll
        for (int kg = 0; kg < 16; ++kg) {
            const float* s = src + (size_t)row * Dd + kg * 32 + quad * 8;
            const float4 v0 = ((const float4*)s)[0];
            const float4 v1 = ((const float4*)s)[1];
            sq += v0.x*v0.x + v0.y*v0.y + v0.z*v0.z + v0.w*v0.w
                + v1.x*v1.x + v1.y*v1.y + v1.z*v1.z + v1.w*v1.w;
            uint4 pk;
            pk.x = (unsigned)f2bf(v0.x) | ((unsigned)f2bf(v0.y) << 16);
            pk.y = (unsigned)f2bf(v0.z) | ((unsigned)f2bf(v0.w) << 16);
            pk.z = (unsigned)f2bf(v1.x) | ((unsigned)f2bf(v1.y) << 16);
            pk.w = (unsigned)f2bf(v1.z) | ((unsigned)f2bf(v1.w) << 16);
            *(uint4*)(dst + ((size_t)g * 16 + kg) * 512 + lane * 8) = pk;
        }
        sq += __shfl_xor(sq, 16);
        sq += __shfl_xor(sq, 32);
        if (lane < 16) nrm[row] = sq;
    } else {
        const int tw = (b - 256) * 4 + wid;           // 0..4095 W tiles
        const int yg = tw & 15, zg = tw >> 4;
        const int y = yg * 16 + l16, z0 = zg * 32 + quad * 8;
        ushort r[8];
        #pragma unroll
        for (int jj = 0; jj < 8; ++jj)
            r[jj] = f2bf(W[(size_t)(z0 + jj) * Yd + y]);
        uint4 pk;
        pk.x = (unsigned)r[0] | ((unsigned)r[1] << 16);
        pk.y = (unsigned)r[2] | ((unsigned)r[3] << 16);
        pk.z = (unsigned)r[4] | ((unsigned)r[5] << 16);
        pk.w = (unsigned)r[6] | ((unsigned)r[7] << 16);
        *(uint4*)(Wf + ((size_t)yg * 256 + zg) * 512 + lane * 8) = pk;
    }
}

// ---- main fused kernel ----
__global__ __launch_bounds__(256, 1) void laplace_hybrid(
    const ushort* __restrict__ Xf, const ushort* __restrict__ Zf,
    const ushort* __restrict__ Wf, const float* __restrict__ xsqg,
    const float* __restrict__ zsqg, float* __restrict__ O)
{
    __shared__ ushort sXf[64 * 512];                  // 64 KB: X tile, frag layout
    __shared__ ushort sP[64 * LDP];                   // 33.8 KB
    const int t = threadIdx.x, wid = t >> 6, lane = t & 63;
    const int l16 = lane & 15, quad = lane >> 4;
    const int row0  = blockIdx.x * BM;                // XCD = blockIdx.x % 8
    const int zbase = blockIdx.y * MPER;              // both chunks: same XCD

    // stage the whole X tile once (contiguous 64 KB in fragment layout)
    {
        const uint4* src = (const uint4*)(Xf + (size_t)row0 * Dd);
        uint4* dst = (uint4*)sXf;
        #pragma unroll
        for (int rep = 0; rep < 16; ++rep)
            dst[rep * 256 + t] = src[rep * 256 + t];
    }

    // row norms in registers (C/D row = quad*4+r)
    float xs[4][4];
    #pragma unroll
    for (int i = 0; i < 4; ++i)
        #pragma unroll
        for (int r = 0; r < 4; ++r)
            xs[i][r] = xsqg[row0 + 16 * i + quad * 4 + r];

    const ushort* pb0 = Zf + ((size_t)((zbase >> 4) + wid * 4) * 16) * 512 + lane * 8;
    const ushort* pw  = Wf + ((size_t)(wid * 4) * 256 + (zbase >> 5)) * 512 + lane * 8;

    f32x4 Oa[4][4];
    #pragma unroll
    for (int i = 0; i < 4; ++i)
        #pragma unroll
        for (int j = 0; j < 4; ++j)
            #pragma unroll
            for (int r = 0; r < 4; ++r) Oa[i][j][r] = 0.0f;

    __syncthreads();   // sXf visible

    for (int mt = 0; mt < MT; ++mt) {
        const ushort* pb = pb0 + (size_t)mt * 16 * 16 * 512;   // +256 z-rows
        float zs4[4];
        #pragma unroll
        for (int j = 0; j < 4; ++j)
            zs4[j] = zsqg[zbase + mt * 256 + wid * 64 + 16 * j + l16];

        f32x4 S[4][4];
        #pragma unroll
        for (int i = 0; i < 4; ++i)
            #pragma unroll
            for (int j = 0; j < 4; ++j)
                #pragma unroll
                for (int r = 0; r < 4; ++r) S[i][j][r] = 0.0f;

        // ---- QK: A from LDS (resident), B direct global; no barriers ----
        #pragma unroll
        for (int kk = 0; kk < 16; ++kk) {
            frag8 a[4], b[4];
            #pragma unroll
            for (int j = 0; j < 4; ++j)
                b[j] = *(const frag8*)(pb + (size_t)j * 8192 + kk * 512);
            #pragma unroll
            for (int i = 0; i < 4; ++i)
                a[i] = *(const frag8*)(sXf + (i * 16 + kk) * 512 + lane * 8);
            #pragma unroll
            for (int i = 0; i < 4; ++i)
                #pragma unroll
                for (int j = 0; j < 4; ++j)
                    S[i][j] = __builtin_amdgcn_mfma_f32_16x16x32_bf16(
                        a[i], b[j], S[i][j], 0, 0, 0);
        }

        __syncthreads();   // prev m-tile's PV done reading sP

        // ---- transform -> sP (C/D: col=l16, row=quad*4+r) ----
        #pragma unroll
        for (int i = 0; i < 4; ++i) {
            const int xl = 16 * i + quad * 4;
            #pragma unroll
            for (int j = 0; j < 4; ++j) {
                const int col = wid * 64 + 16 * j + l16;
                const float zz = zs4[j];
                #pragma unroll
                for (int r = 0; r < 4; ++r) {
                    const float d2 = fmaxf(xs[i][r] + zz - 2.0f * S[i][j][r], 0.0f);
                    sP[(xl + r) * LDP + col] = f2bf(__expf(-0.1f * __builtin_sqrtf(d2)));
                }
            }
        }
        __syncthreads();   // sP visible to all waves

        // ---- PV: O += P[64x256] . W[256x256]; A from LDS, B direct ----
        #pragma unroll
        for (int pv = 0; pv < 8; ++pv) {              // z-group (32 z each)
            frag8 ap[4], bw[4];
            #pragma unroll
            for (int j = 0; j < 4; ++j)
                bw[j] = *(const frag8*)(pw + (size_t)j * 131072 + (mt * 8 + pv) * 512);
            #pragma unroll
            for (int i = 0; i < 4; ++i)
                ap[i] = *(const frag8*)(sP + (16 * i + l16) * LDP + pv * 32 + quad * 8);
            #pragma unroll
            for (int j = 0; j < 4; ++j)
                #pragma unroll
                for (int i = 0; i < 4; ++i)
                    Oa[i][j] = __builtin_amdgcn_mfma_f32_16x16x32_bf16(
                        ap[i], bw[j], Oa[i][j], 0, 0, 0);
        }
    }

    // ---- epilogue: combine MCH=2 chunks via fp32 atomics (XCD-local) ----
    #pragma unroll
    for (int i = 0; i < 4; ++i) {
        const int xr = row0 + 16 * i + quad * 4;
        #pragma unroll
        for (int j = 0; j < 4; ++j) {
            const int col = wid * 64 + 16 * j + l16;
            #pragma unroll
            for (int r = 0; r < 4; ++r)
                atomicAdd(&O[(size_t)(xr + r) * Yd + col], Oa[i][j][r]);
        }
    }
}

// ---- fallback (fp32 VALU fused kernel) if workspace is too small ----
constexpr int FBM = 64, FBN = 64, FBK = 64;
constexpr int FMCH = 4, FMCHUNK = Mm / FMCH, FMSTEPS = FMCHUNK / FBN, FDSTEPS = Dd / FBK;
constexpr int FLDA = FBK + 1, FLDSS = FBN + 1;

__global__ __launch_bounds__(256, 3) void laplace_fused_v1(
    const float* __restrict__ X, const float* __restrict__ Z,
    const float* __restrict__ W, float* __restrict__ O)
{
    __shared__ float sX[FBM * FLDA];
    __shared__ float sZ[FBN * FLDA];
    __shared__ float sS[FBM * FLDSS];
    const int t = threadIdx.x, pr = t >> 4, pc = t & 15, sc4 = pc * 4;
    const int row0 = blockIdx.x * FBM, mbase = blockIdx.y * FMCHUNK;
    float o[4][4][4];
    #pragma unroll
    for (int i = 0; i < 4; ++i)
        for (int yb = 0; yb < 4; ++yb)
            for (int j = 0; j < 4; ++j) o[i][yb][j] = 0.0f;
    for (int ms = 0; ms < FMSTEPS; ++ms) {
        const int zrow0 = mbase + ms * FBN;
        float s[4][4];
        #pragma unroll
        for (int i = 0; i < 4; ++i)
            for (int j = 0; j < 4; ++j) s[i][j] = 0.0f;
        for (int kk = 0; kk < FDSTEPS; ++kk) {
            const int k0 = kk * FBK;
            __syncthreads();
            #pragma unroll
            for (int rep = 0; rep < 4; ++rep) {
                const int r = pr + rep * 16;
                const float4 xv = *reinterpret_cast<const float4*>(X + (size_t)(row0 + r) * Dd + k0 + sc4);
                const float4 zv = *reinterpret_cast<const float4*>(Z + (size_t)(zrow0 + r) * Dd + k0 + sc4);
                float* dx = sX + r * FLDA + sc4;
                dx[0] = xv.x; dx[1] = xv.y; dx[2] = xv.z; dx[3] = xv.w;
                float* dz = sZ + r * FLDA + sc4;
                dz[0] = zv.x; dz[1] = zv.y; dz[2] = zv.z; dz[3] = zv.w;
            }
            __syncthreads();
            #pragma unroll 4
            for (int k = 0; k < FBK; ++k) {
                float xr[4], zc[4];
                #pragma unroll
                for (int i = 0; i < 4; ++i) xr[i] = sX[(pr * 4 + i) * FLDA + k];
                #pragma unroll
                for (int j = 0; j < 4; ++j) zc[j] = sZ[(pc * 4 + j) * FLDA + k];
                #pragma unroll
                for (int i = 0; i < 4; ++i)
                    #pragma unroll
                    for (int j = 0; j < 4; ++j) {
                        const float d = xr[i] - zc[j];
                        s[i][j] = fmaf(d, d, s[i][j]);
                    }
            }
        }
        #pragma unroll
        for (int i = 0; i < 4; ++i)
            for (int j = 0; j < 4; ++j)
                sS[(pr * 4 + i) * FLDSS + sc4 + j] = __expf(-sqrtf(s[i][j]) * 0.1f);
        __syncthreads();
        #pragma unroll 2
        for (int c = 0; c < FBN; ++c) {
            float sv[4];
            #pragma unroll
            for (int i = 0; i < 4; ++i) sv[i] = sS[(pr * 4 + i) * FLDSS + c];
            const float* wrow = W + (size_t)(zrow0 + c) * Yd;
            #pragma unroll
            for (int yb = 0; yb < 4; ++yb) {
                const float4 wv = *reinterpret_cast<const float4*>(wrow + yb * 64 + sc4);
                #pragma unroll
                for (int i = 0; i < 4; ++i) {
                    o[i][yb][0] = fmaf(sv[i], wv.x, o[i][yb][0]);
                    o[i][yb][1] = fmaf(sv[i], wv.y, o[i][yb][1]);
                    o[i][yb][2] = fmaf(sv[i], wv.z, o[i][yb][2]);
                    o[i][yb][3] = fmaf(sv[i], wv.w, o[i][yb][3]);
                }
            }
        }
        __syncthreads();
    }
    #pragma unroll
    for (int i = 0; i < 4; ++i) {
        const size_t rbase = (size_t)(row0 + pr * 4 + i) * Yd;
        #pragma unroll
        for (int yb = 0; yb < 4; ++yb)
            for (int j = 0; j < 4; ++j)
                atomicAdd(O + rbase + yb * 64 + sc4 + j, o[i][yb][j]);
    }
}

extern "C" void kernel_launch(void* const* d_in, const int* in_sizes, int n_in,
                              void* d_out, int out_size, void* d_ws, size_t ws_size,
                              hipStream_t stream) {
    const float* X = (const float*)d_in[0];   // batch   [8192, 512]
    const float* Z = (const float*)d_in[1];   // centers [8192, 512]
    const float* W = (const float*)d_in[2];   // weight  [8192, 256]
    float* O = (float*)d_out;                 // pred    [8192, 256]

    hipMemsetAsync(d_out, 0, (size_t)out_size * sizeof(float), stream);

    if (ws_size < WS_NEED) {
        dim3 grid(Nn / FBM, FMCH);
        laplace_fused_v1<<<grid, dim3(256), 0, stream>>>(X, Z, W, O);
        return;
    }

    char* ws = (char*)d_ws;
    ushort* Xf  = (ushort*)(ws + OFF_XF);
    ushort* Zf  = (ushort*)(ws + OFF_ZF);
    ushort* Wf  = (ushort*)(ws + OFF_WF);
    float*  xsq = (float*)(ws + OFF_XSQ);
    float*  zsq = (float*)(ws + OFF_ZSQ);

    prep_swizzle<<<dim3(256 + 1024), dim3(256), 0, stream>>>(
        X, Z, W, Xf, Zf, Wf, xsq, zsq);

    laplace_hybrid<<<dim3(Nn / BM, MCH), dim3(256), 0, stream>>>(
        Xf, Zf, Wf, xsq, zsq, O);
}

// Round 9
// 244.659 us; speedup vs baseline: 1.4388x; 1.2374x over previous
//
#include <hip/hip_runtime.h>

// Laplacian-kernel regression, fused, bf16 MFMA 16x16x32.
//   d2 = ||x||^2 + ||z||^2 - 2 X.Z^T ; P = exp(-sqrt(d2)/10) ; out = P @ W
// R9: R8's traffic discipline (FETCH 53 MB) + 2 waves/SIMD for TLP.
//   512 thr / 8 waves, BM=128 x BN=256, wave grid 2x4 (64x64, 4x4 frags).
//   X staged in LDS K-halves (64 KB, restaged from L2-hot Xf); Z/W direct
//   global fragment loads (2x wave redundancy -> L1 dedup); sP 67.6 KB.
//   4 barriers/m-tile. Grid (64,4) = 256 blocks = 1/CU, 8 waves/CU.
//   MCH=4 -> 32 MB atomic epilogue (R5 lesson: keep atomics small+XCD-local).

using frag8 = __attribute__((ext_vector_type(8))) short;   // 8 bf16 (4 VGPRs)
using f32x4 = __attribute__((ext_vector_type(4))) float;   // 16x16 C/D frag

constexpr int Nn = 8192, Mm = 8192, Dd = 512, Yd = 256;
constexpr int BM = 128, BN = 256;
constexpr int MCH = 4, MPER = Mm / MCH, MT = MPER / BN;    // 2048, 8
constexpr int LDP = BN + 8;    // 264 ushort rows (528 B, 16B-aligned)

// Fragment-tile layout: frag(g, c) = rows [16g,16g+16) x k [32c,32c+32),
// 512 ushorts at (g*KG + c)*512, element (r,k) at ushort lane*8 + k%8 where
// lane = r%16 + 16*((k%32)/8).  Xf/Zf: KG=16 (K=512). Wf: rows=y, KG=256.

// workspace layout (bytes)
constexpr size_t OFF_XF  = 0;                               // 8 MB
constexpr size_t OFF_ZF  = OFF_XF + (size_t)Nn * Dd * 2;    // 8 MB
constexpr size_t OFF_WF  = OFF_ZF + (size_t)Mm * Dd * 2;    // 4 MB
constexpr size_t OFF_XSQ = OFF_WF + (size_t)Yd * Mm * 2;
constexpr size_t OFF_ZSQ = OFF_XSQ + (size_t)Nn * 4;
constexpr size_t WS_NEED = OFF_ZSQ + (size_t)Mm * 4;        // ~20.1 MB

__device__ __forceinline__ ushort f2bf(float f) {
    unsigned u = __builtin_bit_cast(unsigned, f);
    u += 0x7FFFu + ((u >> 16) & 1u);          // RNE; inputs finite/normal
    return (ushort)(u >> 16);
}

// ---- prep (LDS-tiled, fully coalesced global R/W) ----
// blocks 0..1023: X/Z 16-row groups (cast+swizzle+norms); 1024..1279: W
// 32-z stripes (cast+transpose+swizzle).
__global__ __launch_bounds__(256) void prep_v9(
    const float* __restrict__ X, const float* __restrict__ Z,
    const float* __restrict__ W, ushort* __restrict__ Xf,
    ushort* __restrict__ Zf, ushort* __restrict__ Wf,
    float* __restrict__ xsq, float* __restrict__ zsq)
{
    __shared__ float tile[16 * 516];              // also used as [32][260] for W
    __shared__ float part[256];
    const int t = threadIdx.x, b = blockIdx.x;
    if (b < 1024) {
        const int g = (b < 512) ? b : b - 512;
        const float* src = (b < 512 ? X : Z) + (size_t)g * 16 * Dd;
        ushort* dst = (b < 512 ? Xf : Zf) + (size_t)g * 16 * 512;
        float* nrm = (b < 512 ? xsq : zsq) + g * 16;
        #pragma unroll
        for (int rep = 0; rep < 8; ++rep) {       // 2048 float4, coalesced
            const int idx = rep * 256 + t;
            const int r = idx >> 7, c4 = (idx & 127) * 4;
            const float4 v = *(const float4*)(src + (size_t)r * Dd + c4);
            float* d = tile + r * 516 + c4;
            d[0] = v.x; d[1] = v.y; d[2] = v.z; d[3] = v.w;
        }
        __syncthreads();
        {   // norms: thread t -> row t>>4, 32-elem segment t&15
            const int r = t >> 4, s0 = (t & 15) * 32;
            float sq = 0.0f;
            #pragma unroll
            for (int k = 0; k < 32; ++k) {
                const float v = tile[r * 516 + s0 + k];
                sq += v * v;
            }
            part[t] = sq;
        }
        __syncthreads();
        if (t < 16) {
            float sq = 0.0f;
            #pragma unroll
            for (int k = 0; k < 16; ++k) sq += part[t * 16 + k];
            nrm[t] = sq;
        }
        #pragma unroll
        for (int rep = 0; rep < 4; ++rep) {       // 1024 uint4 frag writes
            const int idx = rep * 256 + t;
            const int kg = idx >> 6, w = idx & 63;
            const int l16 = w & 15, quad = w >> 4;
            const float* s = tile + l16 * 516 + kg * 32 + quad * 8;
            uint4 pk;
            pk.x = (unsigned)f2bf(s[0]) | ((unsigned)f2bf(s[1]) << 16);
            pk.y = (unsigned)f2bf(s[2]) | ((unsigned)f2bf(s[3]) << 16);
            pk.z = (unsigned)f2bf(s[4]) | ((unsigned)f2bf(s[5]) << 16);
            pk.w = (unsigned)f2bf(s[6]) | ((unsigned)f2bf(s[7]) << 16);
            *(uint4*)(dst + (size_t)kg * 512 + w * 8) = pk;
        }
    } else {
        const int zg = b - 1024;                  // 32-z stripe
        const float* src = W + (size_t)zg * 32 * Yd;
        #pragma unroll
        for (int rep = 0; rep < 8; ++rep) {       // 2048 float4, coalesced
            const int idx = rep * 256 + t;
            const int r = idx >> 6, c4 = (idx & 63) * 4;
            const float4 v = *(const float4*)(src + (size_t)r * Yd + c4);
            float* d = tile + r * 260 + c4;
            d[0] = v.x; d[1] = v.y; d[2] = v.z; d[3] = v.w;
        }
        __syncthreads();
        #pragma unroll
        for (int rep = 0; rep < 4; ++rep) {       // 16 y-frags x 64 words
            const int idx = rep * 256 + t;
            const int yg = idx >> 6, w = idx & 63;
            const int l16 = w & 15, quad = w >> 4;
            const int y = yg * 16 + l16;
            ushort rr[8];
            #pragma unroll
            for (int j = 0; j < 8; ++j)
                rr[j] = f2bf(tile[(quad * 8 + j) * 260 + y]);
            uint4 pk;
            pk.x = (unsigned)rr[0] | ((unsigned)rr[1] << 16);
            pk.y = (unsigned)rr[2] | ((unsigned)rr[3] << 16);
            pk.z = (unsigned)rr[4] | ((unsigned)rr[5] << 16);
            pk.w = (unsigned)rr[6] | ((unsigned)rr[7] << 16);
            *(uint4*)(Wf + ((size_t)yg * 256 + zg) * 512 + w * 8) = pk;
        }
    }
}

// ---- main fused kernel ----
__global__ __launch_bounds__(512, 2) void laplace_v9(
    const ushort* __restrict__ Xf, const ushort* __restrict__ Zf,
    const ushort* __restrict__ Wf, const float* __restrict__ xsqg,
    const float* __restrict__ zsqg, float* __restrict__ O)
{
    __shared__ ushort sXh[64 * 512];              // 64 KB: X K-half, 64 frags
    __shared__ ushort sP[BM * LDP];               // 67.6 KB
    const int t = threadIdx.x, wid = t >> 6, lane = t & 63;
    const int l16 = lane & 15, quad = lane >> 4;
    const int wr = wid >> 2, wc = wid & 3;        // wave grid 2x4
    const int row0  = blockIdx.x * BM;            // XCD = blockIdx.x % 8
    const int zbase = blockIdx.y * MPER;
    const int xg0 = row0 >> 4;                    // X 16-row-group base

    float xs[4][4];
    #pragma unroll
    for (int i = 0; i < 4; ++i)
        #pragma unroll
        for (int r = 0; r < 4; ++r)
            xs[i][r] = xsqg[row0 + wr * 64 + 16 * i + quad * 4 + r];

    f32x4 Oa[4][4];
    #pragma unroll
    for (int i = 0; i < 4; ++i)
        #pragma unroll
        for (int j = 0; j < 4; ++j)
            #pragma unroll
            for (int r = 0; r < 4; ++r) Oa[i][j][r] = 0.0f;

    for (int mt = 0; mt < MT; ++mt) {
        const int zg0 = (zbase >> 4) + mt * 16;   // Z 16-row-group base
        float zs4[4];
        #pragma unroll
        for (int j = 0; j < 4; ++j)
            zs4[j] = zsqg[zbase + mt * 256 + wc * 64 + 16 * j + l16];

        f32x4 S[4][4];
        #pragma unroll
        for (int i = 0; i < 4; ++i)
            #pragma unroll
            for (int j = 0; j < 4; ++j)
                #pragma unroll
                for (int r = 0; r < 4; ++r) S[i][j][r] = 0.0f;

        // ---- QK in two K-halves; X from LDS, Z direct global ----
        #pragma unroll
        for (int h = 0; h < 2; ++h) {
            // stage sXh: 64 frags (8 row-groups x 8 k-groups), 4096 uint4.
            // Safe: all waves passed prev barrier => prev readers done.
            #pragma unroll
            for (int rep = 0; rep < 8; ++rep) {
                const int idx = rep * 512 + t;
                const int f = idx >> 6, w = idx & 63;
                *(uint4*)(sXh + f * 512 + w * 8) = *(const uint4*)(
                    Xf + ((size_t)(xg0 + (f >> 3)) * 16 + h * 8 + (f & 7)) * 512 + w * 8);
            }
            __syncthreads();                      // sXh ready (bar_a / bar_b)
            #pragma unroll
            for (int kk = 0; kk < 8; ++kk) {
                frag8 a[4], b[4];
                #pragma unroll
                for (int j = 0; j < 4; ++j)
                    b[j] = *(const frag8*)(Zf +
                        ((size_t)(zg0 + wc * 4 + j) * 16 + h * 8 + kk) * 512 + lane * 8);
                #pragma unroll
                for (int i = 0; i < 4; ++i)
                    a[i] = *(const frag8*)(sXh + ((wr * 4 + i) * 8 + kk) * 512 + lane * 8);
                #pragma unroll
                for (int i = 0; i < 4; ++i)
                    #pragma unroll
                    for (int j = 0; j < 4; ++j)
                        S[i][j] = __builtin_amdgcn_mfma_f32_16x16x32_bf16(
                            a[i], b[j], S[i][j], 0, 0, 0);
            }
            if (h == 0) __syncthreads();          // all QK-h0 reads done (bar_a2)
        }

        // ---- transform -> sP (C/D: col=l16, row=quad*4+r). Safe vs prev PV:
        //      all waves passed this mt's bar_a => prev PV complete. ----
        #pragma unroll
        for (int i = 0; i < 4; ++i) {
            const int xl = wr * 64 + 16 * i + quad * 4;
            #pragma unroll
            for (int j = 0; j < 4; ++j) {
                const int col = wc * 64 + 16 * j + l16;
                const float zz = zs4[j];
                #pragma unroll
                for (int r = 0; r < 4; ++r) {
                    const float d2 = fmaxf(xs[i][r] + zz - 2.0f * S[i][j][r], 0.0f);
                    sP[(xl + r) * LDP + col] = f2bf(__expf(-0.1f * __builtin_sqrtf(d2)));
                }
            }
        }
        __syncthreads();                          // sP visible (bar_c)

        // ---- PV: O += P[128x256].W[256x256]; A from sP, B direct global ----
        const int zgw0 = (zbase >> 5) + mt * 8;   // W 32-z-group base
        #pragma unroll
        for (int pv = 0; pv < 8; ++pv) {
            frag8 ap[4], bw[4];
            #pragma unroll
            for (int j = 0; j < 4; ++j)
                bw[j] = *(const frag8*)(Wf +
                    ((size_t)(wc * 4 + j) * 256 + zgw0 + pv) * 512 + lane * 8);
            #pragma unroll
            for (int i = 0; i < 4; ++i)
                ap[i] = *(const frag8*)(
                    sP + (wr * 64 + 16 * i + l16) * LDP + pv * 32 + quad * 8);
            #pragma unroll
            for (int j = 0; j < 4; ++j)
                #pragma unroll
                for (int i = 0; i < 4; ++i)
                    Oa[i][j] = __builtin_amdgcn_mfma_f32_16x16x32_bf16(
                        ap[i], bw[j], Oa[i][j], 0, 0, 0);
        }
        // next mt stage-h0 safe: all waves passed bar_c => all QK-h1 done.
    }

    // ---- epilogue: combine MCH=4 chunks via fp32 atomics (XCD-local) ----
    #pragma unroll
    for (int i = 0; i < 4; ++i) {
        const int xr = row0 + wr * 64 + 16 * i + quad * 4;
        #pragma unroll
        for (int j = 0; j < 4; ++j) {
            const int col = wc * 64 + 16 * j + l16;
            #pragma unroll
            for (int r = 0; r < 4; ++r)
                atomicAdd(&O[(size_t)(xr + r) * Yd + col], Oa[i][j][r]);
        }
    }
}

// ---- fallback (fp32 VALU fused kernel) if workspace is too small ----
constexpr int FBM = 64, FBN = 64, FBK = 64;
constexpr int FMCH = 4, FMCHUNK = Mm / FMCH, FMSTEPS = FMCHUNK / FBN, FDSTEPS = Dd / FBK;
constexpr int FLDA = FBK + 1, FLDSS = FBN + 1;

__global__ __launch_bounds__(256, 3) void laplace_fused_v1(
    const float* __restrict__ X, const float* __restrict__ Z,
    const float* __restrict__ W, float* __restrict__ O)
{
    __shared__ float sX[FBM * FLDA];
    __shared__ float sZ[FBN * FLDA];
    __shared__ float sS[FBM * FLDSS];
    const int t = threadIdx.x, pr = t >> 4, pc = t & 15, sc4 = pc * 4;
    const int row0 = blockIdx.x * FBM, mbase = blockIdx.y * FMCHUNK;
    float o[4][4][4];
    #pragma unroll
    for (int i = 0; i < 4; ++i)
        for (int yb = 0; yb < 4; ++yb)
            for (int j = 0; j < 4; ++j) o[i][yb][j] = 0.0f;
    for (int ms = 0; ms < FMSTEPS; ++ms) {
        const int zrow0 = mbase + ms * FBN;
        float s[4][4];
        #pragma unroll
        for (int i = 0; i < 4; ++i)
            for (int j = 0; j < 4; ++j) s[i][j] = 0.0f;
        for (int kk = 0; kk < FDSTEPS; ++kk) {
            const int k0 = kk * FBK;
            __syncthreads();
            #pragma unroll
            for (int rep = 0; rep < 4; ++rep) {
                const int r = pr + rep * 16;
                const float4 xv = *reinterpret_cast<const float4*>(X + (size_t)(row0 + r) * Dd + k0 + sc4);
                const float4 zv = *reinterpret_cast<const float4*>(Z + (size_t)(zrow0 + r) * Dd + k0 + sc4);
                float* dx = sX + r * FLDA + sc4;
                dx[0] = xv.x; dx[1] = xv.y; dx[2] = xv.z; dx[3] = xv.w;
                float* dz = sZ + r * FLDA + sc4;
                dz[0] = zv.x; dz[1] = zv.y; dz[2] = zv.z; dz[3] = zv.w;
            }
            __syncthreads();
            #pragma unroll 4
            for (int k = 0; k < FBK; ++k) {
                float xr[4], zc[4];
                #pragma unroll
                for (int i = 0; i < 4; ++i) xr[i] = sX[(pr * 4 + i) * FLDA + k];
                #pragma unroll
                for (int j = 0; j < 4; ++j) zc[j] = sZ[(pc * 4 + j) * FLDA + k];
                #pragma unroll
                for (int i = 0; i < 4; ++i)
                    #pragma unroll
                    for (int j = 0; j < 4; ++j) {
                        const float d = xr[i] - zc[j];
                        s[i][j] = fmaf(d, d, s[i][j]);
                    }
            }
        }
        #pragma unroll
        for (int i = 0; i < 4; ++i)
            for (int j = 0; j < 4; ++j)
                sS[(pr * 4 + i) * FLDSS + sc4 + j] = __expf(-sqrtf(s[i][j]) * 0.1f);
        __syncthreads();
        #pragma unroll 2
        for (int c = 0; c < FBN; ++c) {
            float sv[4];
            #pragma unroll
            for (int i = 0; i < 4; ++i) sv[i] = sS[(pr * 4 + i) * FLDSS + c];
            const float* wrow = W + (size_t)(zrow0 + c) * Yd;
            #pragma unroll
            for (int yb = 0; yb < 4; ++yb) {
                const float4 wv = *reinterpret_cast<const float4*>(wrow + yb * 64 + sc4);
                #pragma unroll
                for (int i = 0; i < 4; ++i) {
                    o[i][yb][0] = fmaf(sv[i], wv.x, o[i][yb][0]);
                    o[i][yb][1] = fmaf(sv[i], wv.y, o[i][yb][1]);
                    o[i][yb][2] = fmaf(sv[i], wv.z, o[i][yb][2]);
                    o[i][yb][3] = fmaf(sv[i], wv.w, o[i][yb][3]);
                }
            }
        }
        __syncthreads();
    }
    #pragma unroll
    for (int i = 0; i < 4; ++i) {
        const size_t rbase = (size_t)(row0 + pr * 4 + i) * Yd;
        #pragma unroll
        for (int yb = 0; yb < 4; ++yb)
            for (int j = 0; j < 4; ++j)
                atomicAdd(O + rbase + yb * 64 + sc4 + j, o[i][yb][j]);
    }
}

extern "C" void kernel_launch(void* const* d_in, const int* in_sizes, int n_in,
                              void* d_out, int out_size, void* d_ws, size_t ws_size,
                              hipStream_t stream) {
    const float* X = (const float*)d_in[0];   // batch   [8192, 512]
    const float* Z = (const float*)d_in[1];   // centers [8192, 512]
    const float* W = (const float*)d_in[2];   // weight  [8192, 256]
    float* O = (float*)d_out;                 // pred    [8192, 256]

    hipMemsetAsync(d_out, 0, (size_t)out_size * sizeof(float), stream);

    if (ws_size < WS_NEED) {
        dim3 grid(Nn / FBM, FMCH);
        laplace_fused_v1<<<grid, dim3(256), 0, stream>>>(X, Z, W, O);
        return;
    }

    char* ws = (char*)d_ws;
    ushort* Xf  = (ushort*)(ws + OFF_XF);
    ushort* Zf  = (ushort*)(ws + OFF_ZF);
    ushort* Wf  = (ushort*)(ws + OFF_WF);
    float*  xsq = (float*)(ws + OFF_XSQ);
    float*  zsq = (float*)(ws + OFF_ZSQ);

    prep_v9<<<dim3(1024 + 256), dim3(256), 0, stream>>>(
        X, Z, W, Xf, Zf, Wf, xsq, zsq);

    laplace_v9<<<dim3(Nn / BM, MCH), dim3(512), 0, stream>>>(
        Xf, Zf, Wf, xsq, zsq, O);
}